// Round 1
// baseline (808.960 us; speedup 1.0000x reference)
//
#include <hip/hip_runtime.h>

#define BB 16
#define TT 12
#define NN 1024
#define DD 64
#define EE 32
#define MM (TT*NN)          // 12288 rows per batch
#define ROWS (BB*MM)        // 196608 total rows
#define CPB 48              // blocks per batch for K2/K4 (48*256 = 12288 rows)
#define LN_EPS 1e-5f

__device__ __forceinline__ float wave_sum64(float v){
  #pragma unroll
  for (int off = 32; off; off >>= 1) v += __shfl_xor(v, off);
  return v;
}

// ---------------- K1: fused STGCN: u = 0.5*(x[t-1]+x[t]); g1=u@W1^T+b1; g2=u@W2^T+b2;
//                  h = relu(g1*g2)+g1; out1 = LN(h + x) ----------------
__global__ __launch_bounds__(256, 2)
void k1_stgcn(const float* __restrict__ x,
              const float* __restrict__ W1, const float* __restrict__ b1,
              const float* __restrict__ W2, const float* __restrict__ b2,
              const float* __restrict__ lng, const float* __restrict__ lnb,
              float* __restrict__ out1)
{
  __shared__ __align__(16) float ubuf[4][DD];
  const int lane = threadIdx.x & 63;
  const int wid  = threadIdx.x >> 6;

  // each lane holds row o=lane of W1 and W2 in registers (static indexing only)
  float w1[DD], w2[DD];
  #pragma unroll
  for (int j = 0; j < DD/4; ++j){
    float4 a = *reinterpret_cast<const float4*>(W1 + lane*DD + 4*j);
    w1[4*j+0]=a.x; w1[4*j+1]=a.y; w1[4*j+2]=a.z; w1[4*j+3]=a.w;
    float4 c = *reinterpret_cast<const float4*>(W2 + lane*DD + 4*j);
    w2[4*j+0]=c.x; w2[4*j+1]=c.y; w2[4*j+2]=c.z; w2[4*j+3]=c.w;
  }
  const float bb1 = b1[lane], bb2 = b2[lane];
  const float gam = lng[lane], bet = lnb[lane];

  const int wstride = gridDim.x * 4;
  for (int r = blockIdx.x*4 + wid; r < ROWS; r += wstride){
    const int t = (r / NN) % TT;
    const size_t base = (size_t)r * DD;
    const float xc = x[base + lane];
    const float xp = (t > 0) ? x[base - (size_t)NN*DD + lane] : 0.f;
    const float u  = 0.5f * (xc + xp);
    ubuf[wid][lane] = u;
    __builtin_amdgcn_wave_barrier();
    float g1 = bb1, g2 = bb2;
    #pragma unroll
    for (int j = 0; j < DD/4; ++j){
      const float4 uv = *reinterpret_cast<const float4*>(&ubuf[wid][4*j]); // uniform -> LDS broadcast
      g1 = fmaf(uv.x, w1[4*j+0], g1);  g2 = fmaf(uv.x, w2[4*j+0], g2);
      g1 = fmaf(uv.y, w1[4*j+1], g1);  g2 = fmaf(uv.y, w2[4*j+1], g2);
      g1 = fmaf(uv.z, w1[4*j+2], g1);  g2 = fmaf(uv.z, w2[4*j+2], g2);
      g1 = fmaf(uv.w, w1[4*j+3], g1);  g2 = fmaf(uv.w, w2[4*j+3], g2);
    }
    __builtin_amdgcn_wave_barrier();
    const float h = fmaxf(g1*g2, 0.f) + g1;
    const float s = h + xc;
    const float mean = wave_sum64(s) * (1.f/DD);
    const float d0 = s - mean;
    const float var = wave_sum64(d0*d0) * (1.f/DD);
    out1[base + lane] = d0 * rsqrtf(var + LN_EPS) * gam + bet;
  }
}

// ---------------- K2: assign = softmax(x @ edge_clf); accumulate hf[b,e,d] = sum_m a[m,e]*x[m,d] ----------------
__global__ __launch_bounds__(256, 4)
void k2_hyper1(const float* __restrict__ x, const float* __restrict__ clf,
               float* __restrict__ assign_ws, float* __restrict__ hf)
{
  __shared__ __align__(16) float xbuf[4][DD];
  __shared__ __align__(16) float abuf[4][EE];
  const int lane = threadIdx.x & 63;
  const int wid  = threadIdx.x >> 6;
  const int b = blockIdx.x / CPB;
  const int chunk = blockIdx.x % CPB;
  const int e = lane & 31;
  const int half = lane >> 5;

  // lane (e,half) holds clf[d][e] for d in [32*half, 32*half+32)
  float clfreg[EE];
  #pragma unroll
  for (int j = 0; j < EE; ++j) clfreg[j] = clf[(half*32 + j)*EE + e];

  float hfacc[EE];   // reg j: hf[e=j][d=lane] partial
  #pragma unroll
  for (int j = 0; j < EE; ++j) hfacc[j] = 0.f;

  const int rpw = (MM / CPB) / 4;   // 64 rows per wave
  for (int it = 0; it < rpw; ++it){
    const int mrow = chunk*(MM/CPB) + wid*rpw + it;
    const size_t ridx = (size_t)b*MM + mrow;
    const float xv = x[ridx*DD + lane];
    xbuf[wid][lane] = xv;
    __builtin_amdgcn_wave_barrier();
    float part = 0.f;
    #pragma unroll
    for (int j = 0; j < 8; ++j){
      const float4 uv = *reinterpret_cast<const float4*>(&xbuf[wid][half*32 + 4*j]);
      part = fmaf(uv.x, clfreg[4*j+0], part);
      part = fmaf(uv.y, clfreg[4*j+1], part);
      part = fmaf(uv.z, clfreg[4*j+2], part);
      part = fmaf(uv.w, clfreg[4*j+3], part);
    }
    const float logit = part + __shfl_xor(part, 32);   // both halves hold full logit[e]
    float mx = logit;
    #pragma unroll
    for (int off = 16; off; off >>= 1) mx = fmaxf(mx, __shfl_xor(mx, off));
    const float ex = expf(logit - mx);
    float sm = ex;
    #pragma unroll
    for (int off = 16; off; off >>= 1) sm += __shfl_xor(sm, off);
    const float a = ex / sm;
    if (half == 0) assign_ws[ridx*EE + e] = a;
    abuf[wid][e] = a;   // both halves write identical value (benign)
    __builtin_amdgcn_wave_barrier();
    #pragma unroll
    for (int j = 0; j < 8; ++j){
      const float4 av = *reinterpret_cast<const float4*>(&abuf[wid][4*j]);
      hfacc[4*j+0] = fmaf(av.x, xv, hfacc[4*j+0]);
      hfacc[4*j+1] = fmaf(av.y, xv, hfacc[4*j+1]);
      hfacc[4*j+2] = fmaf(av.z, xv, hfacc[4*j+2]);
      hfacc[4*j+3] = fmaf(av.w, xv, hfacc[4*j+3]);
    }
    __builtin_amdgcn_wave_barrier();
  }
  #pragma unroll
  for (int j = 0; j < EE; ++j)
    atomicAdd(&hf[((size_t)b*EE + j)*DD + lane], hfacc[j]);
}

// ---------------- K3: hyper_out = relu(edge_map @ hf) + hf  (tiny: B x 32 x 64) ----------------
__global__ void k3_edge(const float* __restrict__ hf, const float* __restrict__ em,
                        float* __restrict__ ho)
{
  __shared__ float ems[EE*EE];
  __shared__ float hfs[EE*DD];
  const int b = blockIdx.x;
  const int tid = threadIdx.x;
  for (int i = tid; i < EE*EE; i += 256) ems[i] = em[i];
  for (int i = tid; i < EE*DD; i += 256) hfs[i] = hf[(size_t)b*EE*DD + i];
  __syncthreads();
  for (int i = tid; i < EE*DD; i += 256){
    const int e = i >> 6, d = i & 63;
    float acc = 0.f;
    #pragma unroll
    for (int f = 0; f < EE; ++f) acc = fmaf(ems[e*EE+f], hfs[f*DD+d], acc);
    ho[(size_t)b*EE*DD + i] = fmaxf(acc, 0.f) + hfs[e*DD+d];
  }
}

// ---------------- K4: y = relu(assign @ hyper_out); out2 = LN(y + x); xout = 0.5*(out1+out2) ----------------
__global__ __launch_bounds__(256, 4)
void k4_combine(const float* __restrict__ x, const float* __restrict__ out1,
                const float* __restrict__ assign_ws, const float* __restrict__ ho,
                const float* __restrict__ hg, const float* __restrict__ hb,
                float* __restrict__ xout)
{
  __shared__ __align__(16) float hos[EE*DD];
  __shared__ __align__(16) float abuf[4][EE];
  const int lane = threadIdx.x & 63;
  const int wid  = threadIdx.x >> 6;
  const int b = blockIdx.x / CPB;
  const int chunk = blockIdx.x % CPB;
  for (int i = threadIdx.x; i < EE*DD; i += 256) hos[i] = ho[(size_t)b*EE*DD + i];
  __syncthreads();
  const float gam = hg[lane], bet = hb[lane];
  const int rpw = (MM / CPB) / 4;
  for (int it = 0; it < rpw; ++it){
    const int mrow = chunk*(MM/CPB) + wid*rpw + it;
    const size_t ridx = (size_t)b*MM + mrow;
    const float xc = x[ridx*DD + lane];
    const float o1 = out1[ridx*DD + lane];
    if (lane < EE) abuf[wid][lane] = assign_ws[ridx*EE + lane];
    __builtin_amdgcn_wave_barrier();
    float y = 0.f;
    #pragma unroll
    for (int j = 0; j < 8; ++j){
      const float4 av = *reinterpret_cast<const float4*>(&abuf[wid][4*j]);
      y = fmaf(av.x, hos[(4*j+0)*DD + lane], y);
      y = fmaf(av.y, hos[(4*j+1)*DD + lane], y);
      y = fmaf(av.z, hos[(4*j+2)*DD + lane], y);
      y = fmaf(av.w, hos[(4*j+3)*DD + lane], y);
    }
    __builtin_amdgcn_wave_barrier();
    const float s = fmaxf(y, 0.f) + xc;
    const float mean = wave_sum64(s) * (1.f/DD);
    const float d0 = s - mean;
    const float var = wave_sum64(d0*d0) * (1.f/DD);
    const float o2 = d0 * rsqrtf(var + LN_EPS) * gam + bet;
    xout[ridx*DD + lane] = 0.5f*(o1 + o2);
  }
}

extern "C" void kernel_launch(void* const* d_in, const int* in_sizes, int n_in,
                              void* d_out, int out_size, void* d_ws, size_t ws_size,
                              hipStream_t stream)
{
  (void)in_sizes; (void)n_in; (void)out_size; (void)ws_size;
  const float* x0  = (const float*)d_in[0];
  const float* W1  = (const float*)d_in[1];
  const float* b1  = (const float*)d_in[2];
  const float* W2  = (const float*)d_in[3];
  const float* b2  = (const float*)d_in[4];
  const float* lng = (const float*)d_in[5];
  const float* lnb = (const float*)d_in[6];
  const float* clf = (const float*)d_in[7];
  const float* em  = (const float*)d_in[8];
  const float* hg  = (const float*)d_in[9];
  const float* hb  = (const float*)d_in[10];
  float* out = (float*)d_out;

  // workspace layout (floats): x ping buffer | assign | hf | ho   (~76 MB total)
  float* ws_x   = (float*)d_ws;
  float* assign = ws_x + (size_t)ROWS*DD;
  float* hf     = assign + (size_t)ROWS*EE;
  float* ho     = hf + (size_t)BB*EE*DD;

  for (int i = 0; i < 3; ++i){
    const float* xin = (i == 0) ? x0 : ws_x;
    float* xout = (i == 2) ? out : ws_x;
    // out1 lives in d_out (scratch for depths 0/1; row-local in-place combine at depth 2)
    k1_stgcn<<<2048, 256, 0, stream>>>(xin, W1 + i*DD*DD, b1 + i*DD,
                                       W2 + i*DD*DD, b2 + i*DD,
                                       lng + i*DD, lnb + i*DD, out);
    hipMemsetAsync(hf, 0, (size_t)BB*EE*DD*sizeof(float), stream);
    k2_hyper1<<<BB*CPB, 256, 0, stream>>>(xin, clf, assign, hf);
    k3_edge<<<BB, 256, 0, stream>>>(hf, em, ho);
    k4_combine<<<BB*CPB, 256, 0, stream>>>(xin, out, assign, ho, hg, hb, xout);
  }
}